// Round 8
// baseline (171.802 us; speedup 1.0000x reference)
//
#include <hip/hip_runtime.h>
#include <hip/hip_bf16.h>

// Problem constants
#define B_  2
#define T_  4
#define N_  512
#define D_  768
#define H_  12
#define DH_ 64
#define TOTAL_SPK_ (B_ * H_ * T_ * N_ * N_)  // 25165824
#define NBLK_SCORE_ 768                       // 32 n-tiles x 24 bh

typedef unsigned short u16;
typedef __attribute__((ext_vector_type(8))) __bf16 bf16x8;
typedef __attribute__((ext_vector_type(4))) float f32x4;
typedef __attribute__((ext_vector_type(4))) u16 u16x4;
typedef __attribute__((ext_vector_type(8))) u16 u16x8;
typedef __attribute__((address_space(1))) const unsigned int glds_src;
typedef __attribute__((address_space(3))) unsigned int glds_dst;

__device__ __forceinline__ u16 f2bf(float f) {
    unsigned int u = __builtin_bit_cast(unsigned int, f);
    u += 0x7fffu + ((u >> 16) & 1u);          // RNE
    return (u16)(u >> 16);
}

// ---------------------------------------------------------------------------
// Stage nrows rows (multiple of 8) of a [*][64]-bf16 LDS tile (128 B rows)
// from row-major global. Linear LDS dest + pre-swizzled global source column
// (rule #21); read side applies byte ^= (row&7)<<4.
// ---------------------------------------------------------------------------
__device__ __forceinline__ void stage64(u16* lds, const u16* g, int gld,
                                        int lrow0, int nrows, int grow0, int k0, int lane)
{
    const int sub = lane >> 3;
    const int csrc = (((lane & 7) ^ sub) << 4);
    #pragma unroll
    for (int j = 0; j < nrows; j += 8) {
        const u16* src = g + (size_t)(grow0 + j + sub) * gld + k0 + (csrc >> 1);
        __builtin_amdgcn_global_load_lds((glds_src*)src,
                                         (glds_dst*)(lds + (lrow0 + j) * 64),
                                         16, 0, 0);
    }
}

// Read one 16x32 A/B fragment (8 bf16/lane) from a swizzled [*][64] tile.
__device__ __forceinline__ bf16x8 ldfrag(const u16* lds, int rowbase, int kelem, int lane)
{
    const int r = rowbase + (lane & 15);
    const int cb = (((kelem + ((lane >> 4) << 3)) << 1)) ^ ((r & 7) << 4);
    return *reinterpret_cast<const bf16x8*>(
        reinterpret_cast<const char*>(lds) + (size_t)r * 128 + cb);
}

#define MFMA(a, b, c) __builtin_amdgcn_mfma_f32_16x16x32_bf16((a), (b), (c), 0, 0, 0)

// ---------------------------------------------------------------------------
// Kernel 0: cast fp32 -> bf16 (x and the four weight matrices)
// ---------------------------------------------------------------------------
__global__ __launch_bounds__(256) void cast_all(
    const float* __restrict__ x,  const float* __restrict__ wq, const float* __restrict__ wk,
    const float* __restrict__ wv, const float* __restrict__ wo,
    u16* __restrict__ xb, u16* __restrict__ wqb, u16* __restrict__ wkb,
    u16* __restrict__ wvb, u16* __restrict__ wob)
{
    const int z = blockIdx.y;
    const float* s; u16* d; int n4;
    switch (z) {
        case 0: s = x;  d = xb;  n4 = (B_*T_*N_*D_) / 4; break;
        case 1: s = wq; d = wqb; n4 = (D_*D_) / 4; break;
        case 2: s = wk; d = wkb; n4 = (D_*D_) / 4; break;
        case 3: s = wv; d = wvb; n4 = (D_*D_) / 4; break;
        default: s = wo; d = wob; n4 = (D_*D_) / 4; break;
    }
    const int i = blockIdx.x * 256 + threadIdx.x;
    if (i < n4) {
        float4 v = reinterpret_cast<const float4*>(s)[i];
        u16x4 o = { f2bf(v.x), f2bf(v.y), f2bf(v.z), f2bf(v.w) };
        reinterpret_cast<u16x4*>(d)[i] = o;
    }
}

// ---------------------------------------------------------------------------
// Kernel 1: QKV projection, bf16 MFMA NT-GEMM, 2-phase LDS double-buffer.
// y = x @ W^T, M=4096 N=768 K=768.  q,k stored [bh][t][n][64]; v stored
// TRANSPOSED vT[bh][t][dh][n].  (unchanged from R4)
// ---------------------------------------------------------------------------
__global__ __launch_bounds__(256) void proj_mfma(
    const u16* __restrict__ xb,
    const u16* __restrict__ wqb, const u16* __restrict__ wkb, const u16* __restrict__ wvb,
    u16* __restrict__ q, u16* __restrict__ k, u16* __restrict__ vT)
{
    const int z = blockIdx.z;
    const u16* __restrict__ w = (z == 0) ? wqb : (z == 1) ? wkb : wvb;
    const int m0 = blockIdx.x * 128;
    const int n0 = blockIdx.y * 128;
    __shared__ u16 As[2][128 * 64];
    __shared__ u16 Bs[2][128 * 64];
    const int tid = threadIdx.x, lane = tid & 63, wid = tid >> 6;
    const int wr = wid >> 1, wc = wid & 1;

    f32x4 acc[4][4];
    #pragma unroll
    for (int i = 0; i < 4; ++i)
        #pragma unroll
        for (int j = 0; j < 4; ++j) acc[i][j] = f32x4{0.f, 0.f, 0.f, 0.f};

    stage64(As[0], xb, D_, wid * 32, 32, m0 + wid * 32, 0, lane);
    stage64(Bs[0], w,  D_, wid * 32, 32, n0 + wid * 32, 0, lane);
    __syncthreads();

    const int NK = D_ / 64;                 // 12
    for (int kt = 0; kt < NK; ++kt) {
        const int cur = kt & 1;
        if (kt + 1 < NK) {
            stage64(As[cur ^ 1], xb, D_, wid * 32, 32, m0 + wid * 32, (kt + 1) * 64, lane);
            stage64(Bs[cur ^ 1], w,  D_, wid * 32, 32, n0 + wid * 32, (kt + 1) * 64, lane);
            __builtin_amdgcn_sched_barrier(0);
        }
        bf16x8 af[4][2], bfr[4][2];
        #pragma unroll
        for (int mi = 0; mi < 4; ++mi) {
            af[mi][0] = ldfrag(As[cur], wr * 64 + mi * 16, 0, lane);
            af[mi][1] = ldfrag(As[cur], wr * 64 + mi * 16, 32, lane);
        }
        #pragma unroll
        for (int ni = 0; ni < 4; ++ni) {
            bfr[ni][0] = ldfrag(Bs[cur], wc * 64 + ni * 16, 0, lane);
            bfr[ni][1] = ldfrag(Bs[cur], wc * 64 + ni * 16, 32, lane);
        }
        #pragma unroll
        for (int kk = 0; kk < 2; ++kk)
            #pragma unroll
            for (int mi = 0; mi < 4; ++mi)
                #pragma unroll
                for (int ni = 0; ni < 4; ++ni)
                    acc[mi][ni] = MFMA(af[mi][kk], bfr[ni][kk], acc[mi][ni]);
        __syncthreads();
    }

    if (z < 2) {
        u16* __restrict__ dst = (z == 0) ? q : k;
        #pragma unroll
        for (int mi = 0; mi < 4; ++mi)
            #pragma unroll
            for (int ni = 0; ni < 4; ++ni) {
                const int col = n0 + wc * 64 + ni * 16 + (lane & 15);
                const int h = col >> 6, dh = col & 63;
                const int row0 = m0 + wr * 64 + mi * 16 + ((lane >> 4) << 2);
                const int b = row0 >> 11, t = (row0 >> 9) & 3, n = row0 & 511;
                u16* p = dst + (size_t)(((b * H_ + h) * T_ + t) * N_ + n) * 64 + dh;
                f32x4 a = acc[mi][ni];
                p[0] = f2bf(a[0]); p[64] = f2bf(a[1]); p[128] = f2bf(a[2]); p[192] = f2bf(a[3]);
            }
    } else {
        #pragma unroll
        for (int mi = 0; mi < 4; ++mi)
            #pragma unroll
            for (int ni = 0; ni < 4; ++ni) {
                const int col = n0 + wc * 64 + ni * 16 + (lane & 15);
                const int h = col >> 6, dh = col & 63;
                const int row0 = m0 + wr * 64 + mi * 16 + ((lane >> 4) << 2);
                const int b = row0 >> 11, t = (row0 >> 9) & 3, n = row0 & 511;
                f32x4 a = acc[mi][ni];
                u16x4 o = { f2bf(a[0]), f2bf(a[1]), f2bf(a[2]), f2bf(a[3]) };
                *reinterpret_cast<u16x4*>(
                    vT + (size_t)(((b * H_ + h) * T_ + t) * 64 + dh) * N_ + n) = o;
            }
    }
}

// ---------------------------------------------------------------------------
// Kernel 2: FUSED scores + LIF + PV (structure unchanged from R7) with
// XCD-chunked bijective block swizzle (T1).  R7 PMC: FETCH_SIZE 52 MB vs
// 18 MB working set, dur ~= fetch/1.1TB/s -> HBM-re-fetch-bound because the
// 32 blocks sharing a bh's k/vT slabs round-robin across 8 XCD L2s.
// Swizzle: swz = (bid%8)*96 + bid/8  (768%8==0 -> bijective); each XCD gets
// 96 consecutive logical blocks = 3 whole bh-groups; per-XCD working set
// ~2.3 MB < 4 MB L2.  Per-block work mapping identical -> bit-identical
// output (tripwire: absmax must stay 1.625).
// ---------------------------------------------------------------------------
__global__ __launch_bounds__(256) void score_lif_pv(
    const u16* __restrict__ q, const u16* __restrict__ k, const u16* __restrict__ vT,
    u16* __restrict__ pre, unsigned int* __restrict__ cnt)
{
    // T1 XCD-chunked swizzle over flattened 768-block grid
    const int bid = blockIdx.y * 32 + blockIdx.x;
    const int swz = (bid & 7) * (NBLK_SCORE_ / 8) + (bid >> 3);
    const int bh = swz >> 5;             // 0..23
    const int n0 = (swz & 31) * 16;      // q-row tile base (16 rows)
    const int b = bh / H_, h = bh % H_;
    __shared__ u16 SPK[4 * 2048];        // per-wave [2 sub][16 rows][64 cols] swizzled
    __shared__ f32x4 PACC[4][4][64];     // [wave][ni][lane] PV partials, 16 KB
    __shared__ int red4[4];
    const int tid = threadIdx.x, lane = tid & 63, w = tid >> 6;
    const int lo = lane & 15, hi = lane >> 4;
    u16* spkw = SPK + w * 2048;
    const int mq0 = w * 128;             // this wave's m-quadrant base

    const float beta = 0.95122942450071400f;  // exp(-1/20)
    f32x4 mem[8];                             // membranes for 16 rows x 128 m / 64 lanes
    #pragma unroll
    for (int i = 0; i < 8; ++i) mem[i] = f32x4{0.f, 0.f, 0.f, 0.f};
    int c = 0;

    for (int t = 0; t < T_; ++t) {
        const u16* qs = q  + (size_t)(bh * T_ + t) * (N_ * 64);
        const u16* ks = k  + (size_t)(bh * T_ + t) * (N_ * 64);
        const u16* vs = vT + (size_t)(bh * T_ + t) * (64 * N_);

        // q A-fragments for the block's 16 rows (each wave loads its own copy)
        bf16x8 qa[2];
        #pragma unroll
        for (int kk = 0; kk < 2; ++kk)
            qa[kk] = *reinterpret_cast<const bf16x8*>(
                qs + (size_t)(n0 + lo) * 64 + kk * 32 + hi * 8);

        // ---- scores for this wave's 16n x 128m quadrant, K=64 ----
        f32x4 sacc[8];
        #pragma unroll
        for (int ni = 0; ni < 8; ++ni) {
            sacc[ni] = f32x4{0.f, 0.f, 0.f, 0.f};
            #pragma unroll
            for (int kk = 0; kk < 2; ++kk) {
                bf16x8 kb = *reinterpret_cast<const bf16x8*>(
                    ks + (size_t)(mq0 + ni * 16 + lo) * 64 + kk * 32 + hi * 8);
                sacc[ni] = MFMA(qa[kk], kb, sacc[ni]);
            }
        }
        // ---- LIF + spikes -> per-wave swizzled LDS ----
        #pragma unroll
        for (int ni = 0; ni < 8; ++ni) {
            const int cs = (ni & 3) * 16 + lo;       // col within 64-col subtile
            const int sub = ni >> 2;
            #pragma unroll
            for (int r = 0; r < 4; ++r) {
                const int rl = hi * 4 + r;           // row 0..15 in wave tile
                float mm = beta * mem[ni][r] + sacc[ni][r] * 0.125f;
                const bool sp = (mm >= 0.5f);
                mem[ni][r] = mm - (sp ? 0.5f : 0.0f);
                spkw[sub * 1024 + rl * 64 + ((((cs << 1) ^ ((rl & 7) << 4))) >> 1)]
                    = sp ? (u16)0x3F80u : (u16)0u;
                c += sp ? 1 : 0;
            }
        }
        // ---- PV partial: pacc_w = spk(16 x 128) @ v(128 x 64) ----
        f32x4 pacc[4];
        #pragma unroll
        for (int ni = 0; ni < 4; ++ni) pacc[ni] = f32x4{0.f, 0.f, 0.f, 0.f};
        #pragma unroll
        for (int sub = 0; sub < 2; ++sub)
            #pragma unroll
            for (int kk = 0; kk < 2; ++kk) {
                bf16x8 af = ldfrag(spkw + sub * 1024, 0, kk * 32, lane);
                #pragma unroll
                for (int ni = 0; ni < 4; ++ni) {
                    bf16x8 vb = *reinterpret_cast<const bf16x8*>(
                        vs + (size_t)(ni * 16 + lo) * N_
                           + mq0 + sub * 64 + kk * 32 + hi * 8);
                    pacc[ni] = MFMA(af, vb, pacc[ni]);
                }
            }

        // ---- cross-wave reduction of PV partials ----
        #pragma unroll
        for (int ni = 0; ni < 4; ++ni) PACC[w][ni][lane] = pacc[ni];
        __syncthreads();
        {
            // wave w takes dh-quadrant ni=w: sum partials in wave order 0,1,2,3
            f32x4 s0 = PACC[0][w][lane];
            f32x4 s1 = PACC[1][w][lane];
            f32x4 s2 = PACC[2][w][lane];
            f32x4 s3 = PACC[3][w][lane];
            f32x4 sum = ((s0 + s1) + s2) + s3;
            const int dh = w * 16 + lo;
            const int n = n0 + hi * 4;
            u16* p = pre + (size_t)((b * T_ + t) * N_ + n) * D_ + h * 64 + dh;
            p[0] = f2bf(sum[0]); p[D_] = f2bf(sum[1]);
            p[2 * D_] = f2bf(sum[2]); p[3 * D_] = f2bf(sum[3]);
        }
        __syncthreads();   // protect PACC before next t's writes
    }

    // spike-count reduction
    #pragma unroll
    for (int off = 32; off > 0; off >>= 1) c += __shfl_down(c, off);
    if (lane == 0) red4[w] = c;
    __syncthreads();
    if (tid == 0)
        cnt[swz] = (unsigned int)(red4[0] + red4[1] + red4[2] + red4[3]);
}

// ---------------------------------------------------------------------------
// Kernel 3: output projection, bf16 MFMA NT-GEMM, 2-phase double-buffer.
// out = pre @ wo^T (fp32 out)   (unchanged from R4)
// ---------------------------------------------------------------------------
__global__ __launch_bounds__(256) void wo_mfma(
    const u16* __restrict__ pre, const u16* __restrict__ wob, float* __restrict__ out)
{
    const int m0 = blockIdx.x * 128;
    const int n0 = blockIdx.y * 128;
    __shared__ u16 As[2][128 * 64];
    __shared__ u16 Bs[2][128 * 64];
    const int tid = threadIdx.x, lane = tid & 63, wid = tid >> 6;
    const int wr = wid >> 1, wc = wid & 1;

    f32x4 acc[4][4];
    #pragma unroll
    for (int i = 0; i < 4; ++i)
        #pragma unroll
        for (int j = 0; j < 4; ++j) acc[i][j] = f32x4{0.f, 0.f, 0.f, 0.f};

    stage64(As[0], pre, D_, wid * 32, 32, m0 + wid * 32, 0, lane);
    stage64(Bs[0], wob, D_, wid * 32, 32, n0 + wid * 32, 0, lane);
    __syncthreads();

    const int NK = D_ / 64;                 // 12
    for (int kt = 0; kt < NK; ++kt) {
        const int cur = kt & 1;
        if (kt + 1 < NK) {
            stage64(As[cur ^ 1], pre, D_, wid * 32, 32, m0 + wid * 32, (kt + 1) * 64, lane);
            stage64(Bs[cur ^ 1], wob, D_, wid * 32, 32, n0 + wid * 32, (kt + 1) * 64, lane);
            __builtin_amdgcn_sched_barrier(0);
        }
        bf16x8 af[4][2], bfr[4][2];
        #pragma unroll
        for (int mi = 0; mi < 4; ++mi) {
            af[mi][0] = ldfrag(As[cur], wr * 64 + mi * 16, 0, lane);
            af[mi][1] = ldfrag(As[cur], wr * 64 + mi * 16, 32, lane);
        }
        #pragma unroll
        for (int ni = 0; ni < 4; ++ni) {
            bfr[ni][0] = ldfrag(Bs[cur], wc * 64 + ni * 16, 0, lane);
            bfr[ni][1] = ldfrag(Bs[cur], wc * 64 + ni * 16, 32, lane);
        }
        #pragma unroll
        for (int kk = 0; kk < 2; ++kk)
            #pragma unroll
            for (int mi = 0; mi < 4; ++mi)
                #pragma unroll
                for (int ni = 0; ni < 4; ++ni)
                    acc[mi][ni] = MFMA(af[mi][kk], bfr[ni][kk], acc[mi][ni]);
        __syncthreads();
    }

    #pragma unroll
    for (int mi = 0; mi < 4; ++mi)
        #pragma unroll
        for (int ni = 0; ni < 4; ++ni) {
            const int col = n0 + wc * 64 + ni * 16 + (lane & 15);
            const int row0 = m0 + wr * 64 + mi * 16 + ((lane >> 4) << 2);
            f32x4 a = acc[mi][ni];
            float* p = out + (size_t)row0 * D_ + col;
            p[0] = a[0]; p[D_] = a[1]; p[2 * D_] = a[2]; p[3 * D_] = a[3];
        }
}

// ---------------------------------------------------------------------------
// Kernel 4: attn_rate = sum(per-block counts) / 25165824   (no atomics)
// ---------------------------------------------------------------------------
__global__ __launch_bounds__(256) void rate_kernel(
    const unsigned int* __restrict__ cnt, float* __restrict__ out)
{
    __shared__ unsigned int red4[4];
    const int tid = threadIdx.x;
    unsigned int c = 0;
    for (int i = tid; i < NBLK_SCORE_; i += 256) c += cnt[i];
    #pragma unroll
    for (int off = 32; off > 0; off >>= 1) c += __shfl_down(c, off);
    if ((tid & 63) == 0) red4[tid >> 6] = c;
    __syncthreads();
    if (tid == 0) {
        double total = (double)red4[0] + red4[1] + red4[2] + red4[3];
        out[0] = (float)(total / (double)TOTAL_SPK_);
    }
}

// ---------------------------------------------------------------------------
extern "C" void kernel_launch(void* const* d_in, const int* in_sizes, int n_in,
                              void* d_out, int out_size, void* d_ws, size_t ws_size,
                              hipStream_t stream)
{
    const float* x  = (const float*)d_in[0];
    const float* wq = (const float*)d_in[1];
    const float* wk = (const float*)d_in[2];
    const float* wv = (const float*)d_in[3];
    const float* wo = (const float*)d_in[4];
    float* out = (float*)d_out;

    // workspace (u16 units): xb | wqb wkb wvb wob | q k vT | pre | cnt
    u16* xb  = (u16*)d_ws;                          // 3145728
    u16* wqb = xb + (size_t)B_ * T_ * N_ * D_;      // 589824 each
    u16* wkb = wqb + D_ * D_;
    u16* wvb = wkb + D_ * D_;
    u16* wob = wvb + D_ * D_;
    u16* q   = wob + D_ * D_;                       // 3145728 each
    u16* k   = q + (size_t)B_ * H_ * T_ * N_ * 64;
    u16* vT  = k + (size_t)B_ * H_ * T_ * N_ * 64;
    u16* pre = vT + (size_t)B_ * H_ * T_ * N_ * 64; // 3145728
    unsigned int* cnt = (unsigned int*)(pre + (size_t)B_ * T_ * N_ * D_);
    // total ~37 MB

    cast_all    <<<dim3((B_*T_*N_*D_/4 + 255) / 256, 5), 256, 0, stream>>>(
                    x, wq, wk, wv, wo, xb, wqb, wkb, wvb, wob);
    proj_mfma   <<<dim3(32, 6, 3), 256, 0, stream>>>(xb, wqb, wkb, wvb, q, k, vT);
    score_lif_pv<<<dim3(32, 24), 256, 0, stream>>>(q, k, vT, pre, cnt);
    wo_mfma     <<<dim3(32, 6), 256, 0, stream>>>(pre, wob, out);
    rate_kernel <<<1, 256, 0, stream>>>(cnt, out + (size_t)B_ * T_ * N_ * D_);
}

// Round 9
// 168.836 us; speedup vs baseline: 1.0176x; 1.0176x over previous
//
#include <hip/hip_runtime.h>
#include <hip/hip_bf16.h>

// Problem constants
#define B_  2
#define T_  4
#define N_  512
#define D_  768
#define H_  12
#define DH_ 64
#define TOTAL_SPK_ (B_ * H_ * T_ * N_ * N_)  // 25165824
#define NBLK_SCORE_ 768                       // 32 n-tiles x 24 bh

typedef unsigned short u16;
typedef __attribute__((ext_vector_type(8))) __bf16 bf16x8;
typedef __attribute__((ext_vector_type(4))) float f32x4;
typedef __attribute__((ext_vector_type(4))) u16 u16x4;
typedef __attribute__((ext_vector_type(8))) u16 u16x8;
typedef __attribute__((address_space(1))) const unsigned int glds_src;
typedef __attribute__((address_space(3))) unsigned int glds_dst;

__device__ __forceinline__ u16 f2bf(float f) {
    unsigned int u = __builtin_bit_cast(unsigned int, f);
    u += 0x7fffu + ((u >> 16) & 1u);          // RNE
    return (u16)(u >> 16);
}

// ---------------------------------------------------------------------------
// Stage nrows rows (multiple of 8) of a [*][64]-bf16 LDS tile (128 B rows)
// from row-major global. Linear LDS dest + pre-swizzled global source column
// (rule #21); read side applies byte ^= (row&7)<<4.
// ---------------------------------------------------------------------------
__device__ __forceinline__ void stage64(u16* lds, const u16* g, int gld,
                                        int lrow0, int nrows, int grow0, int k0, int lane)
{
    const int sub = lane >> 3;
    const int csrc = (((lane & 7) ^ sub) << 4);
    #pragma unroll
    for (int j = 0; j < nrows; j += 8) {
        const u16* src = g + (size_t)(grow0 + j + sub) * gld + k0 + (csrc >> 1);
        __builtin_amdgcn_global_load_lds((glds_src*)src,
                                         (glds_dst*)(lds + (lrow0 + j) * 64),
                                         16, 0, 0);
    }
}

// Read one 16x32 A/B fragment (8 bf16/lane) from a swizzled [*][64] tile.
__device__ __forceinline__ bf16x8 ldfrag(const u16* lds, int rowbase, int kelem, int lane)
{
    const int r = rowbase + (lane & 15);
    const int cb = (((kelem + ((lane >> 4) << 3)) << 1)) ^ ((r & 7) << 4);
    return *reinterpret_cast<const bf16x8*>(
        reinterpret_cast<const char*>(lds) + (size_t)r * 128 + cb);
}

#define MFMA(a, b, c) __builtin_amdgcn_mfma_f32_16x16x32_bf16((a), (b), (c), 0, 0, 0)

// ---------------------------------------------------------------------------
// Kernel 0: cast fp32 -> bf16 (x and the four weight matrices)
// ---------------------------------------------------------------------------
__global__ __launch_bounds__(256) void cast_all(
    const float* __restrict__ x,  const float* __restrict__ wq, const float* __restrict__ wk,
    const float* __restrict__ wv, const float* __restrict__ wo,
    u16* __restrict__ xb, u16* __restrict__ wqb, u16* __restrict__ wkb,
    u16* __restrict__ wvb, u16* __restrict__ wob)
{
    const int z = blockIdx.y;
    const float* s; u16* d; int n4;
    switch (z) {
        case 0: s = x;  d = xb;  n4 = (B_*T_*N_*D_) / 4; break;
        case 1: s = wq; d = wqb; n4 = (D_*D_) / 4; break;
        case 2: s = wk; d = wkb; n4 = (D_*D_) / 4; break;
        case 3: s = wv; d = wvb; n4 = (D_*D_) / 4; break;
        default: s = wo; d = wob; n4 = (D_*D_) / 4; break;
    }
    const int i = blockIdx.x * 256 + threadIdx.x;
    if (i < n4) {
        float4 v = reinterpret_cast<const float4*>(s)[i];
        u16x4 o = { f2bf(v.x), f2bf(v.y), f2bf(v.z), f2bf(v.w) };
        reinterpret_cast<u16x4*>(d)[i] = o;
    }
}

// ---------------------------------------------------------------------------
// Kernel 1: QKV projection, bf16 MFMA NT-GEMM, 2-phase LDS double-buffer.
// y = x @ W^T, M=4096 N=768 K=768.  q,k stored [bh][t][n][64]; v stored
// TRANSPOSED vT[bh][t][dh][n].
// __launch_bounds__(256,2): live regs ~160 (acc 64 + frags 64 + staging);
// default heuristic capped at 112 VGPR -> scratch spills in the K-loop.
// ---------------------------------------------------------------------------
__global__ __launch_bounds__(256, 2) void proj_mfma(
    const u16* __restrict__ xb,
    const u16* __restrict__ wqb, const u16* __restrict__ wkb, const u16* __restrict__ wvb,
    u16* __restrict__ q, u16* __restrict__ k, u16* __restrict__ vT)
{
    const int z = blockIdx.z;
    const u16* __restrict__ w = (z == 0) ? wqb : (z == 1) ? wkb : wvb;
    const int m0 = blockIdx.x * 128;
    const int n0 = blockIdx.y * 128;
    __shared__ u16 As[2][128 * 64];
    __shared__ u16 Bs[2][128 * 64];
    const int tid = threadIdx.x, lane = tid & 63, wid = tid >> 6;
    const int wr = wid >> 1, wc = wid & 1;

    f32x4 acc[4][4];
    #pragma unroll
    for (int i = 0; i < 4; ++i)
        #pragma unroll
        for (int j = 0; j < 4; ++j) acc[i][j] = f32x4{0.f, 0.f, 0.f, 0.f};

    stage64(As[0], xb, D_, wid * 32, 32, m0 + wid * 32, 0, lane);
    stage64(Bs[0], w,  D_, wid * 32, 32, n0 + wid * 32, 0, lane);
    __syncthreads();

    const int NK = D_ / 64;                 // 12
    for (int kt = 0; kt < NK; ++kt) {
        const int cur = kt & 1;
        if (kt + 1 < NK) {
            stage64(As[cur ^ 1], xb, D_, wid * 32, 32, m0 + wid * 32, (kt + 1) * 64, lane);
            stage64(Bs[cur ^ 1], w,  D_, wid * 32, 32, n0 + wid * 32, (kt + 1) * 64, lane);
            __builtin_amdgcn_sched_barrier(0);
        }
        bf16x8 af[4][2], bfr[4][2];
        #pragma unroll
        for (int mi = 0; mi < 4; ++mi) {
            af[mi][0] = ldfrag(As[cur], wr * 64 + mi * 16, 0, lane);
            af[mi][1] = ldfrag(As[cur], wr * 64 + mi * 16, 32, lane);
        }
        #pragma unroll
        for (int ni = 0; ni < 4; ++ni) {
            bfr[ni][0] = ldfrag(Bs[cur], wc * 64 + ni * 16, 0, lane);
            bfr[ni][1] = ldfrag(Bs[cur], wc * 64 + ni * 16, 32, lane);
        }
        #pragma unroll
        for (int kk = 0; kk < 2; ++kk)
            #pragma unroll
            for (int mi = 0; mi < 4; ++mi)
                #pragma unroll
                for (int ni = 0; ni < 4; ++ni)
                    acc[mi][ni] = MFMA(af[mi][kk], bfr[ni][kk], acc[mi][ni]);
        __syncthreads();
    }

    if (z < 2) {
        u16* __restrict__ dst = (z == 0) ? q : k;
        #pragma unroll
        for (int mi = 0; mi < 4; ++mi)
            #pragma unroll
            for (int ni = 0; ni < 4; ++ni) {
                const int col = n0 + wc * 64 + ni * 16 + (lane & 15);
                const int h = col >> 6, dh = col & 63;
                const int row0 = m0 + wr * 64 + mi * 16 + ((lane >> 4) << 2);
                const int b = row0 >> 11, t = (row0 >> 9) & 3, n = row0 & 511;
                u16* p = dst + (size_t)(((b * H_ + h) * T_ + t) * N_ + n) * 64 + dh;
                f32x4 a = acc[mi][ni];
                p[0] = f2bf(a[0]); p[64] = f2bf(a[1]); p[128] = f2bf(a[2]); p[192] = f2bf(a[3]);
            }
    } else {
        #pragma unroll
        for (int mi = 0; mi < 4; ++mi)
            #pragma unroll
            for (int ni = 0; ni < 4; ++ni) {
                const int col = n0 + wc * 64 + ni * 16 + (lane & 15);
                const int h = col >> 6, dh = col & 63;
                const int row0 = m0 + wr * 64 + mi * 16 + ((lane >> 4) << 2);
                const int b = row0 >> 11, t = (row0 >> 9) & 3, n = row0 & 511;
                f32x4 a = acc[mi][ni];
                u16x4 o = { f2bf(a[0]), f2bf(a[1]), f2bf(a[2]), f2bf(a[3]) };
                *reinterpret_cast<u16x4*>(
                    vT + (size_t)(((b * H_ + h) * T_ + t) * 64 + dh) * N_ + n) = o;
            }
    }
}

// ---------------------------------------------------------------------------
// Kernel 2: FUSED scores + LIF + PV with T1 XCD swizzle (structure = R8).
// __launch_bounds__(256,2): live regs ~140 (mem 32 + sacc 32 + pacc 16 +
// qa 8 + addressing). R8 showed VGPR_Count=80 -> the compiler's occupancy
// heuristic spilled accumulators/membranes to scratch (L2-resident, invisible
// in FETCH_SIZE) -> the ~25k cy/t latency floor. Forcing the 2-wave/EU tier
// gives a 256-VGPR budget -> no spill. Numerics bit-identical (absmax 1.625).
// ---------------------------------------------------------------------------
__global__ __launch_bounds__(256, 2) void score_lif_pv(
    const u16* __restrict__ q, const u16* __restrict__ k, const u16* __restrict__ vT,
    u16* __restrict__ pre, unsigned int* __restrict__ cnt)
{
    // T1 XCD-chunked swizzle over flattened 768-block grid
    const int bid = blockIdx.y * 32 + blockIdx.x;
    const int swz = (bid & 7) * (NBLK_SCORE_ / 8) + (bid >> 3);
    const int bh = swz >> 5;             // 0..23
    const int n0 = (swz & 31) * 16;      // q-row tile base (16 rows)
    const int b = bh / H_, h = bh % H_;
    __shared__ u16 SPK[4 * 2048];        // per-wave [2 sub][16 rows][64 cols] swizzled
    __shared__ f32x4 PACC[4][4][64];     // [wave][ni][lane] PV partials, 16 KB
    __shared__ int red4[4];
    const int tid = threadIdx.x, lane = tid & 63, w = tid >> 6;
    const int lo = lane & 15, hi = lane >> 4;
    u16* spkw = SPK + w * 2048;
    const int mq0 = w * 128;             // this wave's m-quadrant base

    const float beta = 0.95122942450071400f;  // exp(-1/20)
    f32x4 mem[8];                             // membranes for 16 rows x 128 m / 64 lanes
    #pragma unroll
    for (int i = 0; i < 8; ++i) mem[i] = f32x4{0.f, 0.f, 0.f, 0.f};
    int c = 0;

    for (int t = 0; t < T_; ++t) {
        const u16* qs = q  + (size_t)(bh * T_ + t) * (N_ * 64);
        const u16* ks = k  + (size_t)(bh * T_ + t) * (N_ * 64);
        const u16* vs = vT + (size_t)(bh * T_ + t) * (64 * N_);

        // q A-fragments for the block's 16 rows (each wave loads its own copy)
        bf16x8 qa[2];
        #pragma unroll
        for (int kk = 0; kk < 2; ++kk)
            qa[kk] = *reinterpret_cast<const bf16x8*>(
                qs + (size_t)(n0 + lo) * 64 + kk * 32 + hi * 8);

        // ---- scores for this wave's 16n x 128m quadrant, K=64 ----
        f32x4 sacc[8];
        #pragma unroll
        for (int ni = 0; ni < 8; ++ni) {
            sacc[ni] = f32x4{0.f, 0.f, 0.f, 0.f};
            #pragma unroll
            for (int kk = 0; kk < 2; ++kk) {
                bf16x8 kb = *reinterpret_cast<const bf16x8*>(
                    ks + (size_t)(mq0 + ni * 16 + lo) * 64 + kk * 32 + hi * 8);
                sacc[ni] = MFMA(qa[kk], kb, sacc[ni]);
            }
        }
        // ---- LIF + spikes -> per-wave swizzled LDS ----
        #pragma unroll
        for (int ni = 0; ni < 8; ++ni) {
            const int cs = (ni & 3) * 16 + lo;       // col within 64-col subtile
            const int sub = ni >> 2;
            #pragma unroll
            for (int r = 0; r < 4; ++r) {
                const int rl = hi * 4 + r;           // row 0..15 in wave tile
                float mm = beta * mem[ni][r] + sacc[ni][r] * 0.125f;
                const bool sp = (mm >= 0.5f);
                mem[ni][r] = mm - (sp ? 0.5f : 0.0f);
                spkw[sub * 1024 + rl * 64 + ((((cs << 1) ^ ((rl & 7) << 4))) >> 1)]
                    = sp ? (u16)0x3F80u : (u16)0u;
                c += sp ? 1 : 0;
            }
        }
        // ---- PV partial: pacc_w = spk(16 x 128) @ v(128 x 64) ----
        f32x4 pacc[4];
        #pragma unroll
        for (int ni = 0; ni < 4; ++ni) pacc[ni] = f32x4{0.f, 0.f, 0.f, 0.f};
        #pragma unroll
        for (int sub = 0; sub < 2; ++sub)
            #pragma unroll
            for (int kk = 0; kk < 2; ++kk) {
                bf16x8 af = ldfrag(spkw + sub * 1024, 0, kk * 32, lane);
                #pragma unroll
                for (int ni = 0; ni < 4; ++ni) {
                    bf16x8 vb = *reinterpret_cast<const bf16x8*>(
                        vs + (size_t)(ni * 16 + lo) * N_
                           + mq0 + sub * 64 + kk * 32 + hi * 8);
                    pacc[ni] = MFMA(af, vb, pacc[ni]);
                }
            }

        // ---- cross-wave reduction of PV partials ----
        #pragma unroll
        for (int ni = 0; ni < 4; ++ni) PACC[w][ni][lane] = pacc[ni];
        __syncthreads();
        {
            // wave w takes dh-quadrant ni=w: sum partials in wave order 0,1,2,3
            f32x4 s0 = PACC[0][w][lane];
            f32x4 s1 = PACC[1][w][lane];
            f32x4 s2 = PACC[2][w][lane];
            f32x4 s3 = PACC[3][w][lane];
            f32x4 sum = ((s0 + s1) + s2) + s3;
            const int dh = w * 16 + lo;
            const int n = n0 + hi * 4;
            u16* p = pre + (size_t)((b * T_ + t) * N_ + n) * D_ + h * 64 + dh;
            p[0] = f2bf(sum[0]); p[D_] = f2bf(sum[1]);
            p[2 * D_] = f2bf(sum[2]); p[3 * D_] = f2bf(sum[3]);
        }
        __syncthreads();   // protect PACC before next t's writes
    }

    // spike-count reduction
    #pragma unroll
    for (int off = 32; off > 0; off >>= 1) c += __shfl_down(c, off);
    if (lane == 0) red4[w] = c;
    __syncthreads();
    if (tid == 0)
        cnt[swz] = (unsigned int)(red4[0] + red4[1] + red4[2] + red4[3]);
}

// ---------------------------------------------------------------------------
// Kernel 3: output projection, bf16 MFMA NT-GEMM, 2-phase double-buffer.
// out = pre @ wo^T (fp32 out).  __launch_bounds__(256,2): same spill fix.
// ---------------------------------------------------------------------------
__global__ __launch_bounds__(256, 2) void wo_mfma(
    const u16* __restrict__ pre, const u16* __restrict__ wob, float* __restrict__ out)
{
    const int m0 = blockIdx.x * 128;
    const int n0 = blockIdx.y * 128;
    __shared__ u16 As[2][128 * 64];
    __shared__ u16 Bs[2][128 * 64];
    const int tid = threadIdx.x, lane = tid & 63, wid = tid >> 6;
    const int wr = wid >> 1, wc = wid & 1;

    f32x4 acc[4][4];
    #pragma unroll
    for (int i = 0; i < 4; ++i)
        #pragma unroll
        for (int j = 0; j < 4; ++j) acc[i][j] = f32x4{0.f, 0.f, 0.f, 0.f};

    stage64(As[0], pre, D_, wid * 32, 32, m0 + wid * 32, 0, lane);
    stage64(Bs[0], wob, D_, wid * 32, 32, n0 + wid * 32, 0, lane);
    __syncthreads();

    const int NK = D_ / 64;                 // 12
    for (int kt = 0; kt < NK; ++kt) {
        const int cur = kt & 1;
        if (kt + 1 < NK) {
            stage64(As[cur ^ 1], pre, D_, wid * 32, 32, m0 + wid * 32, (kt + 1) * 64, lane);
            stage64(Bs[cur ^ 1], wob, D_, wid * 32, 32, n0 + wid * 32, (kt + 1) * 64, lane);
            __builtin_amdgcn_sched_barrier(0);
        }
        bf16x8 af[4][2], bfr[4][2];
        #pragma unroll
        for (int mi = 0; mi < 4; ++mi) {
            af[mi][0] = ldfrag(As[cur], wr * 64 + mi * 16, 0, lane);
            af[mi][1] = ldfrag(As[cur], wr * 64 + mi * 16, 32, lane);
        }
        #pragma unroll
        for (int ni = 0; ni < 4; ++ni) {
            bfr[ni][0] = ldfrag(Bs[cur], wc * 64 + ni * 16, 0, lane);
            bfr[ni][1] = ldfrag(Bs[cur], wc * 64 + ni * 16, 32, lane);
        }
        #pragma unroll
        for (int kk = 0; kk < 2; ++kk)
            #pragma unroll
            for (int mi = 0; mi < 4; ++mi)
                #pragma unroll
                for (int ni = 0; ni < 4; ++ni)
                    acc[mi][ni] = MFMA(af[mi][kk], bfr[ni][kk], acc[mi][ni]);
        __syncthreads();
    }

    #pragma unroll
    for (int mi = 0; mi < 4; ++mi)
        #pragma unroll
        for (int ni = 0; ni < 4; ++ni) {
            const int col = n0 + wc * 64 + ni * 16 + (lane & 15);
            const int row0 = m0 + wr * 64 + mi * 16 + ((lane >> 4) << 2);
            f32x4 a = acc[mi][ni];
            float* p = out + (size_t)row0 * D_ + col;
            p[0] = a[0]; p[D_] = a[1]; p[2 * D_] = a[2]; p[3 * D_] = a[3];
        }
}

// ---------------------------------------------------------------------------
// Kernel 4: attn_rate = sum(per-block counts) / 25165824   (no atomics)
// ---------------------------------------------------------------------------
__global__ __launch_bounds__(256) void rate_kernel(
    const unsigned int* __restrict__ cnt, float* __restrict__ out)
{
    __shared__ unsigned int red4[4];
    const int tid = threadIdx.x;
    unsigned int c = 0;
    for (int i = tid; i < NBLK_SCORE_; i += 256) c += cnt[i];
    #pragma unroll
    for (int off = 32; off > 0; off >>= 1) c += __shfl_down(c, off);
    if ((tid & 63) == 0) red4[tid >> 6] = c;
    __syncthreads();
    if (tid == 0) {
        double total = (double)red4[0] + red4[1] + red4[2] + red4[3];
        out[0] = (float)(total / (double)TOTAL_SPK_);
    }
}

// ---------------------------------------------------------------------------
extern "C" void kernel_launch(void* const* d_in, const int* in_sizes, int n_in,
                              void* d_out, int out_size, void* d_ws, size_t ws_size,
                              hipStream_t stream)
{
    const float* x  = (const float*)d_in[0];
    const float* wq = (const float*)d_in[1];
    const float* wk = (const float*)d_in[2];
    const float* wv = (const float*)d_in[3];
    const float* wo = (const float*)d_in[4];
    float* out = (float*)d_out;

    // workspace (u16 units): xb | wqb wkb wvb wob | q k vT | pre | cnt
    u16* xb  = (u16*)d_ws;                          // 3145728
    u16* wqb = xb + (size_t)B_ * T_ * N_ * D_;      // 589824 each
    u16* wkb = wqb + D_ * D_;
    u16* wvb = wkb + D_ * D_;
    u16* wob = wvb + D_ * D_;
    u16* q   = wob + D_ * D_;                       // 3145728 each
    u16* k   = q + (size_t)B_ * H_ * T_ * N_ * 64;
    u16* vT  = k + (size_t)B_ * H_ * T_ * N_ * 64;
    u16* pre = vT + (size_t)B_ * H_ * T_ * N_ * 64; // 3145728
    unsigned int* cnt = (unsigned int*)(pre + (size_t)B_ * T_ * N_ * D_);
    // total ~37 MB

    cast_all    <<<dim3((B_*T_*N_*D_/4 + 255) / 256, 5), 256, 0, stream>>>(
                    x, wq, wk, wv, wo, xb, wqb, wkb, wvb, wob);
    proj_mfma   <<<dim3(32, 6, 3), 256, 0, stream>>>(xb, wqb, wkb, wvb, q, k, vT);
    score_lif_pv<<<dim3(32, 24), 256, 0, stream>>>(q, k, vT, pre, cnt);
    wo_mfma     <<<dim3(32, 6), 256, 0, stream>>>(pre, wob, out);
    rate_kernel <<<1, 256, 0, stream>>>(cnt, out + (size_t)B_ * T_ * N_ * D_);
}